// Round 7
// baseline (317.759 us; speedup 1.0000x reference)
//
#include <hip/hip_runtime.h>
#include <math.h>

typedef _Float16 h16;
typedef _Float16 h16x4 __attribute__((ext_vector_type(4)));
typedef _Float16 h16x8 __attribute__((ext_vector_type(8)));
typedef float    f32x4 __attribute__((ext_vector_type(4)));

#define Bsz 2
#define Tsz 2048
#define Dsz 1024
#define Hn  16
#define DH  64
#define NC  32         // scan chunks
#define NCSH 5
#define CL  (Tsz/NC)   // 64 steps per chunk
#define TS  16         // steps per LDS tile (scan)
#define NTL (CL/TS)    // 4 tiles per chunk
#define LP  68         // padded LDS row (floats) for scan tiles

// ---------------------------------------------------------------------------
__global__ void cvt_w7(const float* __restrict__ s0, const float* __restrict__ s1,
                       const float* __restrict__ s2, const float* __restrict__ s3,
                       const float* __restrict__ s4, const float* __restrict__ s5,
                       const float* __restrict__ s6, h16* __restrict__ dst) {
    int seg = blockIdx.x >> 9;
    int li  = ((blockIdx.x & 511) << 8) + threadIdx.x;
    const float* sp;
    switch (seg) {
        case 0: sp = s0; break; case 1: sp = s1; break; case 2: sp = s2; break;
        case 3: sp = s3; break; case 4: sp = s4; break; case 5: sp = s5; break;
        default: sp = s6; break;
    }
    size_t e = (size_t)li * 8;
    f32x4 a = *(const f32x4*)(sp + e);
    f32x4 b = *(const f32x4*)(sp + e + 4);
    h16x8 o;
    #pragma unroll
    for (int j = 0; j < 4; ++j) { o[j] = (h16)a[j]; o[j + 4] = (h16)b[j]; }
    *(h16x8*)(dst + (size_t)seg * 1048576 + e) = o;
}

// ---------------------------------------------------------------------------
__global__ void mk_xs(const float* __restrict__ x, h16* __restrict__ xs) {
    int li = (blockIdx.x << 8) + threadIdx.x;
    size_t e = (size_t)li * 8;
    int tok = (int)(e >> 10);
    int t   = tok & (Tsz - 1);
    h16x8 o;
    if (t > 0) {
        f32x4 a = *(const f32x4*)(x + e - Dsz);
        f32x4 b = *(const f32x4*)(x + e - Dsz + 4);
        #pragma unroll
        for (int j = 0; j < 4; ++j) { o[j] = (h16)a[j]; o[j + 4] = (h16)b[j]; }
    } else {
        #pragma unroll
        for (int j = 0; j < 8; ++j) o[j] = (h16)0.f;
    }
    *(h16x8*)(xs + e) = o;
}

// ---------------------------------------------------------------------------
__global__ void lerp5(const float* __restrict__ x, const float* __restrict__ dd,
                      const float* __restrict__ mr, const float* __restrict__ mk,
                      const float* __restrict__ mv, const float* __restrict__ mg,
                      const float* __restrict__ mw,
                      h16* __restrict__ ar, h16* __restrict__ ak, h16* __restrict__ av,
                      h16* __restrict__ ag, h16* __restrict__ aw) {
    size_t e = ((size_t)blockIdx.x * 256 + threadIdx.x) * 4;
    int tok = (int)(e >> 10);
    int t   = tok & (Tsz - 1);
    int d   = (int)(e & (Dsz - 1));
    f32x4 xv = *(const f32x4*)(x + e);
    f32x4 xs;
    if (t > 0) xs = *(const f32x4*)(x + e - Dsz);
    else { xs[0] = xs[1] = xs[2] = xs[3] = 0.f; }
    f32x4 dv  = *(const f32x4*)(dd + e);
    f32x4 dxx = xv - xs;
    #define DOMIX(mp, outp) { \
        f32x4 mm = *(const f32x4*)(mp + d); \
        h16x4 ov; \
        _Pragma("unroll") \
        for (int jj = 0; jj < 4; ++jj) { \
            float m = mm[jj] + dv[jj] * (1.f - mm[jj]); \
            ov[jj] = (h16)(xs[jj] + dxx[jj] * m); \
        } \
        *(h16x4*)(outp + e) = ov; }
    DOMIX(mr, ar) DOMIX(mk, ak) DOMIX(mv, av) DOMIX(mg, ag) DOMIX(mw, aw)
    #undef DOMIX
}

// ---------------------------------------------------------------------------
// f16 MFMA GEMM: 2-phase dbuf gld_lds staging (round-6 K-loop, conflicts=0),
// NEW this round:
//  (1) XCD-aware bijective block swizzle: XCD x owns bm-panels 4x..4x+3 for
//      all bn -> per-XCD L2 set = 1MB A + 2MB W (fits 4MB). idx%8 == XCD.
//  (2) LDS-staged coalesced epilogue: C staged via the dead As/Bs LDS in two
//      32KB halves, stored as full 128B-line dwordx4 rows (was 64 scattered
//      dword stores/thread in 64B segments).
// C[4096][1024] = A[4096][1024] * W[1024][1024]^T, f32 out.
// epi: 0=raw, 1=sigmoid(tanh(y)), 2=silu(y), 3=e^-0.5*sigmoid(y)
#define BK 32

__device__ __forceinline__ void gld16(const void* g, void* l) {
    __builtin_amdgcn_global_load_lds(
        (const __attribute__((address_space(1))) void*)g,
        (__attribute__((address_space(3))) void*)l, 16, 0, 0);
}

__device__ __forceinline__ void gemm_body(const h16* __restrict__ A,
                                          const h16* __restrict__ W,
                                          float* __restrict__ C, int epi) {
    __shared__ __align__(16) char smem[32768];   // As[2]:16KB | Bs[2]:16KB ; reused as Cs
    const int tid  = threadIdx.x;
    const int lane = tid & 63;
    const int wave = tid >> 6;
    const int wm = (wave >> 1) * 64;
    const int wn = (wave & 1) * 64;
    // XCD swizzle: hardware XCD = linear dispatch idx % 8 (z-slice is 256 = 0 mod 8).
    // Give XCD g the blocks with bm-panel-group g: idx = s*8 + g, s = (bm&3? )..
    const int lin = blockIdx.y * 8 + blockIdx.x;      // 0..255
    const int g8  = lin & 7, sq = lin >> 3;           // sq 0..31
    const int bm  = (g8 * 4 + (sq >> 3)) * 128;       // 32 panels
    const int bn  = (sq & 7) * 128;                   // 8 col-blocks
    const int K = 1024, N = 1024;

    f32x4 acc[4][4];
    #pragma unroll
    for (int a = 0; a < 4; ++a)
        #pragma unroll
        for (int b = 0; b < 4; ++b) acc[a][b] = (f32x4)(0.f);

    // staging map (round 6, verified): lane l of wave w covers
    // row 64*half + w*16 + (l>>2), phys chunk l&3; source chunk pre-swizzled.
    const int srow = (wave << 4) + (lane >> 2);
    const int scol = (((lane & 3) ^ ((lane >> 3) & 3)) << 3);
    const h16* gA0 = A + (size_t)(bm + srow) * K + scol;
    const h16* gA1 = gA0 + (size_t)64 * K;
    const h16* gB0 = W + (size_t)(bn + srow) * K + scol;
    const h16* gB1 = gB0 + (size_t)64 * K;

    const int pcq = (lane >> 4) ^ ((lane >> 1) & 3);
    const int fro = (lane & 15) * BK + pcq * 8;

    auto As_p = [&](int b) { return (h16*)(smem + b * 8192); };
    auto Bs_p = [&](int b) { return (h16*)(smem + 16384 + b * 8192); };

    auto stage = [&](int b, int k0) {
        gld16(gA0 + k0, As_p(b) + wave * 512);
        gld16(gA1 + k0, As_p(b) + 2048 + wave * 512);
        gld16(gB0 + k0, Bs_p(b) + wave * 512);
        gld16(gB1 + k0, Bs_p(b) + 2048 + wave * 512);
    };
    auto compute = [&](int b) {
        const h16* as = As_p(b); const h16* bs = Bs_p(b);
        h16x8 af[4], bfr[4];
        #pragma unroll
        for (int mi = 0; mi < 4; ++mi)
            af[mi] = *(const h16x8*)(as + (wm + mi * 16) * BK + fro);
        #pragma unroll
        for (int ni = 0; ni < 4; ++ni)
            bfr[ni] = *(const h16x8*)(bs + (wn + ni * 16) * BK + fro);
        #pragma unroll
        for (int mi = 0; mi < 4; ++mi)
            #pragma unroll
            for (int ni = 0; ni < 4; ++ni)
                acc[mi][ni] = __builtin_amdgcn_mfma_f32_16x16x32_f16(
                    af[mi], bfr[ni], acc[mi][ni], 0, 0, 0);
    };

    stage(0, 0);
    __syncthreads();
    for (int t = 0; t < 16; ++t) {
        stage(1, (2 * t + 1) * BK);
        compute(0);
        __syncthreads();
        if (t < 15) stage(0, (2 * t + 2) * BK);
        compute(1);
        __syncthreads();
    }

    // ---- LDS-staged coalesced epilogue (Cs = 64 rows x 128 cols f32, 32KB) ----
    float* Cs = (float*)smem;
    #pragma unroll
    for (int h = 0; h < 2; ++h) {
        if (h) __syncthreads();              // prior half's stores read LDS
        if ((wave >> 1) == h) {
            #pragma unroll
            for (int mi = 0; mi < 4; ++mi)
                #pragma unroll
                for (int ni = 0; ni < 4; ++ni)
                    #pragma unroll
                    for (int j = 0; j < 4; ++j) {
                        float y = acc[mi][ni][j];
                        if (epi == 1)      { float th = tanhf(y); y = 1.f / (1.f + __expf(-th)); }
                        else if (epi == 2) { y = y / (1.f + __expf(-y)); }
                        else if (epi == 3) { y = 0.60653065971263342f / (1.f + __expf(-y)); }
                        int rl = mi * 16 + (lane >> 4) * 4 + j;     // 0..63
                        int cl = wn + ni * 16 + (lane & 15);        // 0..127
                        Cs[rl * 128 + cl] = y;
                    }
        }
        __syncthreads();
        #pragma unroll
        for (int r = 0; r < 8; ++r) {
            int fi  = r * 1024 + tid * 4;
            int row = fi >> 7, col = fi & 127;
            *(f32x4*)(C + (size_t)(bm + 64 * h + row) * N + bn + col) = *(const f32x4*)(Cs + fi);
        }
    }
}

__global__ __launch_bounds__(256) void gemm_bt(const h16* __restrict__ A,
                                               const h16* __restrict__ W,
                                               float* __restrict__ C, int epi) {
    gemm_body(A, W, C, epi);
}

__global__ __launch_bounds__(256) void gemm5(const h16* __restrict__ A0, const h16* __restrict__ A1,
                                             const h16* __restrict__ A2, const h16* __restrict__ A3,
                                             const h16* __restrict__ A4, const h16* __restrict__ Wb,
                                             float* __restrict__ C0, float* __restrict__ C1,
                                             float* __restrict__ C2, float* __restrict__ C3,
                                             float* __restrict__ C4) {
    int z = blockIdx.z;
    const h16* A; float* C; int epi;
    switch (z) {
        case 0: A = A0; C = C0; epi = 0; break;
        case 1: A = A1; C = C1; epi = 0; break;
        case 2: A = A2; C = C2; epi = 0; break;
        case 3: A = A3; C = C3; epi = 2; break;
        default: A = A4; C = C4; epi = 3; break;
    }
    gemm_body(A, Wb + (size_t)(z + 1) * 1048576, C, epi);
}

// ---------------------------------------------------------------------------
// WKV scan with LDS-staged tiles (unchanged).
__global__ __launch_bounds__(256) void wkv_pass1(const float* __restrict__ kk,
                                                 const float* __restrict__ vv,
                                                 const float* __restrict__ ew,
                                                 float* __restrict__ Abuf,
                                                 float* __restrict__ Pbuf) {
    __shared__ float lds[2][3][TS][LP];
    int blk = blockIdx.x;            // bh*NC + c
    int bh = blk >> NCSH, c = blk & (NC - 1);
    int b = bh >> 4, h = bh & 15;
    int tid = threadIdx.x;
    int i = tid >> 2, q = tid & 3, j0 = q * 16;
    int w = tid >> 6, idx = tid & 63;
    int ss = idx >> 2, qq = idx & 3;
    const float* sarr = (w == 0) ? ew : (w == 1) ? kk : vv;

    float st[16];
    #pragma unroll
    for (int jj = 0; jj < 16; ++jj) st[jj] = 0.f;
    float pp = 1.f;

    size_t cbase = ((size_t)b * Tsz + (size_t)c * CL) * Dsz + h * DH;

    if (w < 3) {
        const f32x4* g = (const f32x4*)(sarr + cbase + (size_t)ss * Dsz + qq * 16);
        f32x4 t0 = g[0], t1 = g[1], t2 = g[2], t3 = g[3];
        f32x4* d = (f32x4*)&lds[0][w][ss][qq * 16];
        d[0] = t0; d[1] = t1; d[2] = t2; d[3] = t3;
    }
    __syncthreads();

    for (int tl = 0; tl < NTL; ++tl) {
        int cur = tl & 1;
        f32x4 t0, t1, t2, t3;
        bool pf = (tl + 1 < NTL) && (w < 3);
        if (pf) {
            const f32x4* g = (const f32x4*)(sarr + cbase + (size_t)(tl + 1) * TS * Dsz
                                            + (size_t)ss * Dsz + qq * 16);
            t0 = g[0]; t1 = g[1]; t2 = g[2]; t3 = g[3];
        }
        #pragma unroll 4
        for (int s = 0; s < TS; ++s) {
            float ewi = lds[cur][0][s][i];
            float ki  = lds[cur][1][s][i];
            const float* vrow = &lds[cur][2][s][0];
            f32x4 v0 = *(const f32x4*)(vrow + j0);
            f32x4 v1 = *(const f32x4*)(vrow + j0 + 4);
            f32x4 v2 = *(const f32x4*)(vrow + j0 + 8);
            f32x4 v3 = *(const f32x4*)(vrow + j0 + 12);
            #pragma unroll
            for (int jj = 0; jj < 4; ++jj) {
                st[jj]      = fmaf(st[jj],      ewi, ki * v0[jj]);
                st[jj + 4]  = fmaf(st[jj + 4],  ewi, ki * v1[jj]);
                st[jj + 8]  = fmaf(st[jj + 8],  ewi, ki * v2[jj]);
                st[jj + 12] = fmaf(st[jj + 12], ewi, ki * v3[jj]);
            }
            pp *= ewi;
        }
        if (pf) {
            f32x4* d = (f32x4*)&lds[cur ^ 1][w][ss][qq * 16];
            d[0] = t0; d[1] = t1; d[2] = t2; d[3] = t3;
        }
        __syncthreads();
    }

    size_t ob = (size_t)blk * 4096 + (size_t)i * 64 + j0;
    f32x4* op = (f32x4*)(Abuf + ob);
    #pragma unroll
    for (int g = 0; g < 4; ++g) {
        f32x4 s;
        #pragma unroll
        for (int jj = 0; jj < 4; ++jj) s[jj] = st[g * 4 + jj];
        op[g] = s;
    }
    if (q == 0) Pbuf[blk * 64 + i] = pp;
}

__global__ __launch_bounds__(256) void wkv_combine(const float* __restrict__ Abuf,
                                                   const float* __restrict__ Pbuf,
                                                   float* __restrict__ Sbuf) {
    int bh = blockIdx.x;
    int tid = threadIdx.x;
    int i = tid >> 2, q = tid & 3, j0 = q * 16;
    float s[16];
    #pragma unroll
    for (int jj = 0; jj < 16; ++jj) s[jj] = 0.f;
    for (int c = 0; c < NC; ++c) {
        size_t ob = ((size_t)(bh * NC + c)) * 4096 + (size_t)i * 64 + j0;
        f32x4* sp = (f32x4*)(Sbuf + ob);
        #pragma unroll
        for (int g = 0; g < 4; ++g) {
            f32x4 t;
            #pragma unroll
            for (int jj = 0; jj < 4; ++jj) t[jj] = s[g * 4 + jj];
            sp[g] = t;
        }
        if (c < NC - 1) {
            float pp = Pbuf[(bh * NC + c) * 64 + i];
            const f32x4* ap = (const f32x4*)(Abuf + ob);
            f32x4 a0 = ap[0], a1 = ap[1], a2 = ap[2], a3 = ap[3];
            #pragma unroll
            for (int jj = 0; jj < 4; ++jj) {
                s[jj]      = s[jj]      * pp + a0[jj];
                s[jj + 4]  = s[jj + 4]  * pp + a1[jj];
                s[jj + 8]  = s[jj + 8]  * pp + a2[jj];
                s[jj + 12] = s[jj + 12] * pp + a3[jj];
            }
        }
    }
}

__global__ __launch_bounds__(256) void wkv_pass2(const float* __restrict__ rr,
                                                 const float* __restrict__ kk,
                                                 const float* __restrict__ vv,
                                                 const float* __restrict__ ew,
                                                 const float* __restrict__ Sbuf,
                                                 float* __restrict__ o) {
    __shared__ float lds[2][4][TS][LP];
    int blk = blockIdx.x;
    int bh = blk >> NCSH, c = blk & (NC - 1);
    int b = bh >> 4, h = bh & 15;
    int tid = threadIdx.x;
    int i = tid >> 2, q = tid & 3, j0 = q * 16;
    int w = tid >> 6, idx = tid & 63;
    int ss = idx >> 2, qq = idx & 3;
    const float* sarr = (w == 0) ? ew : (w == 1) ? kk : (w == 2) ? vv : rr;

    float st[16];
    {
        size_t ob = (size_t)blk * 4096 + (size_t)i * 64 + j0;
        const f32x4* sp = (const f32x4*)(Sbuf + ob);
        f32x4 s0 = sp[0], s1 = sp[1], s2 = sp[2], s3 = sp[3];
        #pragma unroll
        for (int jj = 0; jj < 4; ++jj) {
            st[jj] = s0[jj]; st[jj + 4] = s1[jj]; st[jj + 8] = s2[jj]; st[jj + 12] = s3[jj];
        }
    }

    size_t cbase = ((size_t)b * Tsz + (size_t)c * CL) * Dsz + h * DH;

    {
        const f32x4* g = (const f32x4*)(sarr + cbase + (size_t)ss * Dsz + qq * 16);
        f32x4 t0 = g[0], t1 = g[1], t2 = g[2], t3 = g[3];
        f32x4* d = (f32x4*)&lds[0][w][ss][qq * 16];
        d[0] = t0; d[1] = t1; d[2] = t2; d[3] = t3;
    }
    __syncthreads();

    for (int tl = 0; tl < NTL; ++tl) {
        int cur = tl & 1;
        f32x4 t0, t1, t2, t3;
        bool pf = (tl + 1 < NTL);
        if (pf) {
            const f32x4* g = (const f32x4*)(sarr + cbase + (size_t)(tl + 1) * TS * Dsz
                                            + (size_t)ss * Dsz + qq * 16);
            t0 = g[0]; t1 = g[1]; t2 = g[2]; t3 = g[3];
        }
        size_t gt = cbase + (size_t)tl * TS * Dsz;
        #pragma unroll 4
        for (int s = 0; s < TS; ++s) {
            float ewi = lds[cur][0][s][i];
            float ki  = lds[cur][1][s][i];
            const float* vrow = &lds[cur][2][s][0];
            const float* rrow = &lds[cur][3][s][0];
            f32x4 v0 = *(const f32x4*)(vrow + j0);
            f32x4 v1 = *(const f32x4*)(vrow + j0 + 4);
            f32x4 v2 = *(const f32x4*)(vrow + j0 + 8);
            f32x4 v3 = *(const f32x4*)(vrow + j0 + 12);
            f32x4 r0 = *(const f32x4*)(rrow + j0);
            f32x4 r1 = *(const f32x4*)(rrow + j0 + 4);
            f32x4 r2 = *(const f32x4*)(rrow + j0 + 8);
            f32x4 r3 = *(const f32x4*)(rrow + j0 + 12);
            float po = 0.f;
            #pragma unroll
            for (int jj = 0; jj < 4; ++jj) {
                st[jj]      = fmaf(st[jj],      ewi, ki * v0[jj]);
                st[jj + 4]  = fmaf(st[jj + 4],  ewi, ki * v1[jj]);
                st[jj + 8]  = fmaf(st[jj + 8],  ewi, ki * v2[jj]);
                st[jj + 12] = fmaf(st[jj + 12], ewi, ki * v3[jj]);
                po = fmaf(st[jj],      r0[jj], po);
                po = fmaf(st[jj + 4],  r1[jj], po);
                po = fmaf(st[jj + 8],  r2[jj], po);
                po = fmaf(st[jj + 12], r3[jj], po);
            }
            po += __shfl_xor(po, 1, 64);
            po += __shfl_xor(po, 2, 64);
            if (q == 0) o[gt + (size_t)s * Dsz + i] = po;
        }
        if (pf) {
            f32x4* d = (f32x4*)&lds[cur ^ 1][w][ss][qq * 16];
            d[0] = t0; d[1] = t1; d[2] = t2; d[3] = t3;
        }
        __syncthreads();
    }
}

// ---------------------------------------------------------------------------
__global__ __launch_bounds__(256) void gn_gate(const float* __restrict__ o,
                                               const float* __restrict__ g,
                                               const float* __restrict__ gnw,
                                               const float* __restrict__ gnb,
                                               h16* __restrict__ out) {
    int wave = threadIdx.x >> 6, lane = threadIdx.x & 63;
    int grp = blockIdx.x * 4 + wave;     // tok*16 + h
    int h = grp & 15;
    float val = o[(size_t)grp * 64 + lane];
    float s = val, s2 = val * val;
    #pragma unroll
    for (int m = 1; m < 64; m <<= 1) {
        s  += __shfl_xor(s, m, 64);
        s2 += __shfl_xor(s2, m, 64);
    }
    float mean = s * (1.f / 64.f);
    float var  = s2 * (1.f / 64.f) - mean * mean;
    float y = (val - mean) * rsqrtf(var + 0.00064f);
    int d = h * 64 + lane;
    y = y * gnw[d] + gnb[d];
    y *= g[(size_t)grp * 64 + lane];
    out[(size_t)grp * 64 + lane] = (h16)y;
}

// ---------------------------------------------------------------------------
extern "C" void kernel_launch(void* const* d_in, const int* in_sizes, int n_in,
                              void* d_out, int out_size, void* d_ws, size_t ws_size,
                              hipStream_t stream) {
    const float* x      = (const float*)d_in[0];
    const float* ddw    = (const float*)d_in[1];
    const float* mix_r  = (const float*)d_in[2];
    const float* mix_k  = (const float*)d_in[3];
    const float* mix_v  = (const float*)d_in[4];
    const float* mix_g  = (const float*)d_in[5];
    const float* mix_w  = (const float*)d_in[6];
    const float* r_w    = (const float*)d_in[7];
    const float* k_w    = (const float*)d_in[8];
    const float* v_w    = (const float*)d_in[9];
    const float* g_w    = (const float*)d_in[10];
    const float* w_w    = (const float*)d_in[11];
    const float* out_w  = (const float*)d_in[12];
    const float* gnw    = (const float*)d_in[13];
    const float* gnb    = (const float*)d_in[14];

    char* wsb = (char*)d_ws;
    const size_t MB = 1 << 20;
    h16*   wb    = (h16*)  (wsb);             // 14 MB (7 x 2MB f16 weights)
    h16*   xs    = (h16*)  (wsb + 14 * MB);   //  8 MB
    float* dd    = (float*)(wsb + 22 * MB);   // 16 MB
    h16*   a_r   = (h16*)  (wsb + 38 * MB);   //  8 MB each
    h16*   a_k   = (h16*)  (wsb + 46 * MB);
    h16*   a_v   = (h16*)  (wsb + 54 * MB);
    h16*   a_g   = (h16*)  (wsb + 62 * MB);
    h16*   a_w   = (h16*)  (wsb + 70 * MB);
    float* rb    = (float*)(wsb + 78 * MB);   // 16 MB each
    float* kb    = (float*)(wsb + 94 * MB);
    float* vb    = (float*)(wsb + 110 * MB);
    float* gb    = (float*)(wsb + 126 * MB);
    float* ewb   = (float*)(wsb + 142 * MB);
    float* obuf  = (float*)(wsb + 158 * MB);  // 16 MB
    h16*   gated = (h16*)  (wsb + 174 * MB);  //  8 MB  (end: 182 MB)
    // overlays on the a_* region (dead once the 5 projections are done):
    float* Abuf  = (float*)(wsb + 38 * MB);   // 16.78 MB
    float* Sbuf  = (float*)(wsb + 55 * MB);   // 16.78 MB
    float* Pbuf  = (float*)(wsb + 72 * MB);   //  0.25 MB

    // 1. weights -> f16
    cvt_w7<<<7 * 512, 256, 0, stream>>>(ddw, r_w, k_w, v_w, g_w, w_w, out_w, wb);
    // 2. x_shift -> f16
    mk_xs<<<2048, 256, 0, stream>>>(x, xs);
    // 3. dd = sigmoid(tanh(xs @ ddw^T))
    dim3 gg(8, 32);
    gemm_bt<<<gg, 256, 0, stream>>>(xs, wb, dd, 1);
    // 4. 5-way lerp -> f16 activations
    lerp5<<<4096, 256, 0, stream>>>(x, dd, mix_r, mix_k, mix_v, mix_g, mix_w,
                                    a_r, a_k, a_v, a_g, a_w);
    // 5. batched projections (r,k,v,g-silu,w-exp)
    dim3 gg5(8, 32, 5);
    gemm5<<<gg5, 256, 0, stream>>>(a_r, a_k, a_v, a_g, a_w, wb, rb, kb, vb, gb, ewb);
    // 6-8. chunked WKV scan
    wkv_pass1<<<32 * NC, 256, 0, stream>>>(kb, vb, ewb, Abuf, Pbuf);
    wkv_combine<<<32, 256, 0, stream>>>(Abuf, Pbuf, Sbuf);
    wkv_pass2<<<32 * NC, 256, 0, stream>>>(rb, kb, vb, ewb, Sbuf, obuf);
    // 9. GroupNorm + gate
    gn_gate<<<(int)((size_t)Bsz * Tsz * Hn / 4), 256, 0, stream>>>(obuf, gb, gnw, gnb, gated);
    // 10. output projection
    gemm_bt<<<gg, 256, 0, stream>>>(gated, wb + 6 * 1048576, (float*)d_out, 0);
    (void)in_sizes; (void)n_in; (void)out_size; (void)ws_size;
}

// Round 8
// 262.358 us; speedup vs baseline: 1.2112x; 1.2112x over previous
//
#include <hip/hip_runtime.h>
#include <math.h>

typedef _Float16 h16;
typedef _Float16 h16x4 __attribute__((ext_vector_type(4)));
typedef _Float16 h16x8 __attribute__((ext_vector_type(8)));
typedef float    f32x4 __attribute__((ext_vector_type(4)));

#define Bsz 2
#define Tsz 2048
#define Dsz 1024
#define Hn  16
#define DH  64
#define NC  32         // scan chunks
#define NCSH 5
#define CL  (Tsz/NC)   // 64 steps per chunk
#define TS  16         // steps per LDS tile (scan)
#define NTL (CL/TS)    // 4 tiles per chunk
#define LP  68         // padded LDS row (floats) for scan tiles

// ---------------------------------------------------------------------------
__global__ void cvt_w7(const float* __restrict__ s0, const float* __restrict__ s1,
                       const float* __restrict__ s2, const float* __restrict__ s3,
                       const float* __restrict__ s4, const float* __restrict__ s5,
                       const float* __restrict__ s6, h16* __restrict__ dst) {
    int seg = blockIdx.x >> 9;
    int li  = ((blockIdx.x & 511) << 8) + threadIdx.x;
    const float* sp;
    switch (seg) {
        case 0: sp = s0; break; case 1: sp = s1; break; case 2: sp = s2; break;
        case 3: sp = s3; break; case 4: sp = s4; break; case 5: sp = s5; break;
        default: sp = s6; break;
    }
    size_t e = (size_t)li * 8;
    f32x4 a = *(const f32x4*)(sp + e);
    f32x4 b = *(const f32x4*)(sp + e + 4);
    h16x8 o;
    #pragma unroll
    for (int j = 0; j < 4; ++j) { o[j] = (h16)a[j]; o[j + 4] = (h16)b[j]; }
    *(h16x8*)(dst + (size_t)seg * 1048576 + e) = o;
}

// ---------------------------------------------------------------------------
__global__ void mk_xs(const float* __restrict__ x, h16* __restrict__ xs) {
    int li = (blockIdx.x << 8) + threadIdx.x;
    size_t e = (size_t)li * 8;
    int tok = (int)(e >> 10);
    int t   = tok & (Tsz - 1);
    h16x8 o;
    if (t > 0) {
        f32x4 a = *(const f32x4*)(x + e - Dsz);
        f32x4 b = *(const f32x4*)(x + e - Dsz + 4);
        #pragma unroll
        for (int j = 0; j < 4; ++j) { o[j] = (h16)a[j]; o[j + 4] = (h16)b[j]; }
    } else {
        #pragma unroll
        for (int j = 0; j < 8; ++j) o[j] = (h16)0.f;
    }
    *(h16x8*)(xs + e) = o;
}

// ---------------------------------------------------------------------------
__global__ void lerp5(const float* __restrict__ x, const float* __restrict__ dd,
                      const float* __restrict__ mr, const float* __restrict__ mk,
                      const float* __restrict__ mv, const float* __restrict__ mg,
                      const float* __restrict__ mw,
                      h16* __restrict__ ar, h16* __restrict__ ak, h16* __restrict__ av,
                      h16* __restrict__ ag, h16* __restrict__ aw) {
    size_t e = ((size_t)blockIdx.x * 256 + threadIdx.x) * 4;
    int tok = (int)(e >> 10);
    int t   = tok & (Tsz - 1);
    int d   = (int)(e & (Dsz - 1));
    f32x4 xv = *(const f32x4*)(x + e);
    f32x4 xs;
    if (t > 0) xs = *(const f32x4*)(x + e - Dsz);
    else { xs[0] = xs[1] = xs[2] = xs[3] = 0.f; }
    f32x4 dv  = *(const f32x4*)(dd + e);
    f32x4 dxx = xv - xs;
    #define DOMIX(mp, outp) { \
        f32x4 mm = *(const f32x4*)(mp + d); \
        h16x4 ov; \
        _Pragma("unroll") \
        for (int jj = 0; jj < 4; ++jj) { \
            float m = mm[jj] + dv[jj] * (1.f - mm[jj]); \
            ov[jj] = (h16)(xs[jj] + dxx[jj] * m); \
        } \
        *(h16x4*)(outp + e) = ov; }
    DOMIX(mr, ar) DOMIX(mk, ak) DOMIX(mv, av) DOMIX(mg, ag) DOMIX(mw, aw)
    #undef DOMIX
}

// ---------------------------------------------------------------------------
// f16 MFMA GEMM. Round 8: T4 counted-vmcnt pipeline.
//  - 3 LDS buffer pairs (48KB), stage k+2 ahead: 8 loads in flight per wave.
//  - raw s_barrier + asm s_waitcnt vmcnt(8) before compute (NEVER drain to 0
//    in the main loop); plain s_barrier after compute guards buffer overwrite.
//  - XCD swizzle (kept from r7: FETCH 169->63MB): XCD x owns bm-panels
//    4x..4x+3, all bn -> per-XCD L2 set 1MB A + 2MB W.
//  - staging/read chunk swizzle (kept from r6: bank conflicts = 0).
//  - direct global C stores (r7 LDS epilogue reverted: was +18us).
// C[4096][1024] = A[4096][1024] * W[1024][1024]^T, f32 out.
// epi: 0=raw, 1=sigmoid(tanh(y)), 2=silu(y), 3=e^-0.5*sigmoid(y)
#define BK 32

__device__ __forceinline__ void gld16(const void* g, void* l) {
    __builtin_amdgcn_global_load_lds(
        (const __attribute__((address_space(1))) void*)g,
        (__attribute__((address_space(3))) void*)l, 16, 0, 0);
}

__device__ __forceinline__ void gemm_body(const h16* __restrict__ A,
                                          const h16* __restrict__ W,
                                          float* __restrict__ C, int epi) {
    __shared__ h16 As[3][4096];   // 3 x 8KB
    __shared__ h16 Bs[3][4096];   // total 48KB -> 3 blocks/CU
    const int tid  = threadIdx.x;
    const int lane = tid & 63;
    const int wave = tid >> 6;
    const int wm = (wave >> 1) * 64;
    const int wn = (wave & 1) * 64;
    // XCD swizzle: linear id % 8 == XCD (z-stride 256 is 0 mod 8).
    const int lin = blockIdx.y * 8 + blockIdx.x;      // 0..255
    const int g8  = lin & 7, sq = lin >> 3;           // sq 0..31
    const int bm  = (g8 * 4 + (sq >> 3)) * 128;
    const int bn  = (sq & 7) * 128;
    const int K = 1024, N = 1024;

    f32x4 acc[4][4];
    #pragma unroll
    for (int a = 0; a < 4; ++a)
        #pragma unroll
        for (int b = 0; b < 4; ++b) acc[a][b] = (f32x4)(0.f);

    // staging map: lane l of wave w covers row 64*half + w*16 + (l>>2),
    // phys chunk l&3; global source chunk pre-swizzled (both-sides rule).
    const int srow = (wave << 4) + (lane >> 2);
    const int scol = (((lane & 3) ^ ((lane >> 3) & 3)) << 3);
    const h16* gA0 = A + (size_t)(bm + srow) * K + scol;
    const h16* gA1 = gA0 + (size_t)64 * K;
    const h16* gB0 = W + (size_t)(bn + srow) * K + scol;
    const h16* gB1 = gB0 + (size_t)64 * K;

    const int pcq = (lane >> 4) ^ ((lane >> 1) & 3);
    const int fro = (lane & 15) * BK + pcq * 8;

    auto stage = [&](int b, int k0) {
        gld16(gA0 + k0, &As[b][wave * 512]);
        gld16(gA1 + k0, &As[b][2048 + wave * 512]);
        gld16(gB0 + k0, &Bs[b][wave * 512]);
        gld16(gB1 + k0, &Bs[b][2048 + wave * 512]);
    };
    auto compute = [&](int b) {
        const h16* as = As[b]; const h16* bs = Bs[b];
        h16x8 af[4], bfr[4];
        #pragma unroll
        for (int mi = 0; mi < 4; ++mi)
            af[mi] = *(const h16x8*)(as + (wm + mi * 16) * BK + fro);
        #pragma unroll
        for (int ni = 0; ni < 4; ++ni)
            bfr[ni] = *(const h16x8*)(bs + (wn + ni * 16) * BK + fro);
        #pragma unroll
        for (int mi = 0; mi < 4; ++mi)
            #pragma unroll
            for (int ni = 0; ni < 4; ++ni)
                acc[mi][ni] = __builtin_amdgcn_mfma_f32_16x16x32_f16(
                    af[mi], bfr[ni], acc[mi][ni], 0, 0, 0);
    };

    // STEP: stage chunk kk into buf bs; wait until only the 2 newest stages
    // (8 loads) are outstanding -> buf bc complete; barrier; compute; barrier
    // (post-barrier makes next overwrite of bc safe).
    #define STEP(bc, bs, kk) do { \
        stage(bs, (kk) * BK); \
        asm volatile("s_waitcnt vmcnt(8)" ::: "memory"); \
        __builtin_amdgcn_sched_barrier(0); \
        __builtin_amdgcn_s_barrier(); \
        __builtin_amdgcn_sched_barrier(0); \
        compute(bc); \
        __builtin_amdgcn_sched_barrier(0); \
        __builtin_amdgcn_s_barrier(); \
    } while (0)

    stage(0, 0);
    stage(1, BK);
    for (int tt = 0; tt < 10; ++tt) {       // t = 0..29, stages k=2..31
        STEP(0, 2, 3 * tt + 2);
        STEP(1, 0, 3 * tt + 3);
        STEP(2, 1, 3 * tt + 4);
    }
    // t=30: outstanding = stages k30,k31 (8) -> wait k30 (buf0)
    asm volatile("s_waitcnt vmcnt(4)" ::: "memory");
    __builtin_amdgcn_sched_barrier(0);
    __builtin_amdgcn_s_barrier();
    __builtin_amdgcn_sched_barrier(0);
    compute(0);
    // t=31: wait k31 (buf1)
    asm volatile("s_waitcnt vmcnt(0)" ::: "memory");
    __builtin_amdgcn_sched_barrier(0);
    __builtin_amdgcn_s_barrier();
    __builtin_amdgcn_sched_barrier(0);
    compute(1);
    #undef STEP

    const int colb = bn + wn + (lane & 15);
    const int rowb = bm + wm + (lane >> 4) * 4;
    #pragma unroll
    for (int mi = 0; mi < 4; ++mi)
        #pragma unroll
        for (int ni = 0; ni < 4; ++ni)
            #pragma unroll
            for (int j = 0; j < 4; ++j) {
                float y = acc[mi][ni][j];
                if (epi == 1)      { float th = tanhf(y); y = 1.f / (1.f + __expf(-th)); }
                else if (epi == 2) { y = y / (1.f + __expf(-y)); }
                else if (epi == 3) { y = 0.60653065971263342f / (1.f + __expf(-y)); }
                C[(size_t)(rowb + mi * 16 + j) * N + colb + ni * 16] = y;
            }
}

__global__ __launch_bounds__(256) void gemm_bt(const h16* __restrict__ A,
                                               const h16* __restrict__ W,
                                               float* __restrict__ C, int epi) {
    gemm_body(A, W, C, epi);
}

__global__ __launch_bounds__(256) void gemm5(const h16* __restrict__ A0, const h16* __restrict__ A1,
                                             const h16* __restrict__ A2, const h16* __restrict__ A3,
                                             const h16* __restrict__ A4, const h16* __restrict__ Wb,
                                             float* __restrict__ C0, float* __restrict__ C1,
                                             float* __restrict__ C2, float* __restrict__ C3,
                                             float* __restrict__ C4) {
    int z = blockIdx.z;
    const h16* A; float* C; int epi;
    switch (z) {
        case 0: A = A0; C = C0; epi = 0; break;
        case 1: A = A1; C = C1; epi = 0; break;
        case 2: A = A2; C = C2; epi = 0; break;
        case 3: A = A3; C = C3; epi = 2; break;
        default: A = A4; C = C4; epi = 3; break;
    }
    gemm_body(A, Wb + (size_t)(z + 1) * 1048576, C, epi);
}

// ---------------------------------------------------------------------------
// WKV scan with LDS-staged tiles (unchanged).
__global__ __launch_bounds__(256) void wkv_pass1(const float* __restrict__ kk,
                                                 const float* __restrict__ vv,
                                                 const float* __restrict__ ew,
                                                 float* __restrict__ Abuf,
                                                 float* __restrict__ Pbuf) {
    __shared__ float lds[2][3][TS][LP];
    int blk = blockIdx.x;            // bh*NC + c
    int bh = blk >> NCSH, c = blk & (NC - 1);
    int b = bh >> 4, h = bh & 15;
    int tid = threadIdx.x;
    int i = tid >> 2, q = tid & 3, j0 = q * 16;
    int w = tid >> 6, idx = tid & 63;
    int ss = idx >> 2, qq = idx & 3;
    const float* sarr = (w == 0) ? ew : (w == 1) ? kk : vv;

    float st[16];
    #pragma unroll
    for (int jj = 0; jj < 16; ++jj) st[jj] = 0.f;
    float pp = 1.f;

    size_t cbase = ((size_t)b * Tsz + (size_t)c * CL) * Dsz + h * DH;

    if (w < 3) {
        const f32x4* g = (const f32x4*)(sarr + cbase + (size_t)ss * Dsz + qq * 16);
        f32x4 t0 = g[0], t1 = g[1], t2 = g[2], t3 = g[3];
        f32x4* d = (f32x4*)&lds[0][w][ss][qq * 16];
        d[0] = t0; d[1] = t1; d[2] = t2; d[3] = t3;
    }
    __syncthreads();

    for (int tl = 0; tl < NTL; ++tl) {
        int cur = tl & 1;
        f32x4 t0, t1, t2, t3;
        bool pf = (tl + 1 < NTL) && (w < 3);
        if (pf) {
            const f32x4* g = (const f32x4*)(sarr + cbase + (size_t)(tl + 1) * TS * Dsz
                                            + (size_t)ss * Dsz + qq * 16);
            t0 = g[0]; t1 = g[1]; t2 = g[2]; t3 = g[3];
        }
        #pragma unroll 4
        for (int s = 0; s < TS; ++s) {
            float ewi = lds[cur][0][s][i];
            float ki  = lds[cur][1][s][i];
            const float* vrow = &lds[cur][2][s][0];
            f32x4 v0 = *(const f32x4*)(vrow + j0);
            f32x4 v1 = *(const f32x4*)(vrow + j0 + 4);
            f32x4 v2 = *(const f32x4*)(vrow + j0 + 8);
            f32x4 v3 = *(const f32x4*)(vrow + j0 + 12);
            #pragma unroll
            for (int jj = 0; jj < 4; ++jj) {
                st[jj]      = fmaf(st[jj],      ewi, ki * v0[jj]);
                st[jj + 4]  = fmaf(st[jj + 4],  ewi, ki * v1[jj]);
                st[jj + 8]  = fmaf(st[jj + 8],  ewi, ki * v2[jj]);
                st[jj + 12] = fmaf(st[jj + 12], ewi, ki * v3[jj]);
            }
            pp *= ewi;
        }
        if (pf) {
            f32x4* d = (f32x4*)&lds[cur ^ 1][w][ss][qq * 16];
            d[0] = t0; d[1] = t1; d[2] = t2; d[3] = t3;
        }
        __syncthreads();
    }

    size_t ob = (size_t)blk * 4096 + (size_t)i * 64 + j0;
    f32x4* op = (f32x4*)(Abuf + ob);
    #pragma unroll
    for (int g = 0; g < 4; ++g) {
        f32x4 s;
        #pragma unroll
        for (int jj = 0; jj < 4; ++jj) s[jj] = st[g * 4 + jj];
        op[g] = s;
    }
    if (q == 0) Pbuf[blk * 64 + i] = pp;
}

__global__ __launch_bounds__(256) void wkv_combine(const float* __restrict__ Abuf,
                                                   const float* __restrict__ Pbuf,
                                                   float* __restrict__ Sbuf) {
    int bh = blockIdx.x;
    int tid = threadIdx.x;
    int i = tid >> 2, q = tid & 3, j0 = q * 16;
    float s[16];
    #pragma unroll
    for (int jj = 0; jj < 16; ++jj) s[jj] = 0.f;
    for (int c = 0; c < NC; ++c) {
        size_t ob = ((size_t)(bh * NC + c)) * 4096 + (size_t)i * 64 + j0;
        f32x4* sp = (f32x4*)(Sbuf + ob);
        #pragma unroll
        for (int g = 0; g < 4; ++g) {
            f32x4 t;
            #pragma unroll
            for (int jj = 0; jj < 4; ++jj) t[jj] = s[g * 4 + jj];
            sp[g] = t;
        }
        if (c < NC - 1) {
            float pp = Pbuf[(bh * NC + c) * 64 + i];
            const f32x4* ap = (const f32x4*)(Abuf + ob);
            f32x4 a0 = ap[0], a1 = ap[1], a2 = ap[2], a3 = ap[3];
            #pragma unroll
            for (int jj = 0; jj < 4; ++jj) {
                s[jj]      = s[jj]      * pp + a0[jj];
                s[jj + 4]  = s[jj + 4]  * pp + a1[jj];
                s[jj + 8]  = s[jj + 8]  * pp + a2[jj];
                s[jj + 12] = s[jj + 12] * pp + a3[jj];
            }
        }
    }
}

__global__ __launch_bounds__(256) void wkv_pass2(const float* __restrict__ rr,
                                                 const float* __restrict__ kk,
                                                 const float* __restrict__ vv,
                                                 const float* __restrict__ ew,
                                                 const float* __restrict__ Sbuf,
                                                 float* __restrict__ o) {
    __shared__ float lds[2][4][TS][LP];
    int blk = blockIdx.x;
    int bh = blk >> NCSH, c = blk & (NC - 1);
    int b = bh >> 4, h = bh & 15;
    int tid = threadIdx.x;
    int i = tid >> 2, q = tid & 3, j0 = q * 16;
    int w = tid >> 6, idx = tid & 63;
    int ss = idx >> 2, qq = idx & 3;
    const float* sarr = (w == 0) ? ew : (w == 1) ? kk : (w == 2) ? vv : rr;

    float st[16];
    {
        size_t ob = (size_t)blk * 4096 + (size_t)i * 64 + j0;
        const f32x4* sp = (const f32x4*)(Sbuf + ob);
        f32x4 s0 = sp[0], s1 = sp[1], s2 = sp[2], s3 = sp[3];
        #pragma unroll
        for (int jj = 0; jj < 4; ++jj) {
            st[jj] = s0[jj]; st[jj + 4] = s1[jj]; st[jj + 8] = s2[jj]; st[jj + 12] = s3[jj];
        }
    }

    size_t cbase = ((size_t)b * Tsz + (size_t)c * CL) * Dsz + h * DH;

    {
        const f32x4* g = (const f32x4*)(sarr + cbase + (size_t)ss * Dsz + qq * 16);
        f32x4 t0 = g[0], t1 = g[1], t2 = g[2], t3 = g[3];
        f32x4* d = (f32x4*)&lds[0][w][ss][qq * 16];
        d[0] = t0; d[1] = t1; d[2] = t2; d[3] = t3;
    }
    __syncthreads();

    for (int tl = 0; tl < NTL; ++tl) {
        int cur = tl & 1;
        f32x4 t0, t1, t2, t3;
        bool pf = (tl + 1 < NTL);
        if (pf) {
            const f32x4* g = (const f32x4*)(sarr + cbase + (size_t)(tl + 1) * TS * Dsz
                                            + (size_t)ss * Dsz + qq * 16);
            t0 = g[0]; t1 = g[1]; t2 = g[2]; t3 = g[3];
        }
        size_t gt = cbase + (size_t)tl * TS * Dsz;
        #pragma unroll 4
        for (int s = 0; s < TS; ++s) {
            float ewi = lds[cur][0][s][i];
            float ki  = lds[cur][1][s][i];
            const float* vrow = &lds[cur][2][s][0];
            const float* rrow = &lds[cur][3][s][0];
            f32x4 v0 = *(const f32x4*)(vrow + j0);
            f32x4 v1 = *(const f32x4*)(vrow + j0 + 4);
            f32x4 v2 = *(const f32x4*)(vrow + j0 + 8);
            f32x4 v3 = *(const f32x4*)(vrow + j0 + 12);
            f32x4 r0 = *(const f32x4*)(rrow + j0);
            f32x4 r1 = *(const f32x4*)(rrow + j0 + 4);
            f32x4 r2 = *(const f32x4*)(rrow + j0 + 8);
            f32x4 r3 = *(const f32x4*)(rrow + j0 + 12);
            float po = 0.f;
            #pragma unroll
            for (int jj = 0; jj < 4; ++jj) {
                st[jj]      = fmaf(st[jj],      ewi, ki * v0[jj]);
                st[jj + 4]  = fmaf(st[jj + 4],  ewi, ki * v1[jj]);
                st[jj + 8]  = fmaf(st[jj + 8],  ewi, ki * v2[jj]);
                st[jj + 12] = fmaf(st[jj + 12], ewi, ki * v3[jj]);
                po = fmaf(st[jj],      r0[jj], po);
                po = fmaf(st[jj + 4],  r1[jj], po);
                po = fmaf(st[jj + 8],  r2[jj], po);
                po = fmaf(st[jj + 12], r3[jj], po);
            }
            po += __shfl_xor(po, 1, 64);
            po += __shfl_xor(po, 2, 64);
            if (q == 0) o[gt + (size_t)s * Dsz + i] = po;
        }
        if (pf) {
            f32x4* d = (f32x4*)&lds[cur ^ 1][w][ss][qq * 16];
            d[0] = t0; d[1] = t1; d[2] = t2; d[3] = t3;
        }
        __syncthreads();
    }
}

// ---------------------------------------------------------------------------
__global__ __launch_bounds__(256) void gn_gate(const float* __restrict__ o,
                                               const float* __restrict__ g,
                                               const float* __restrict__ gnw,
                                               const float* __restrict__ gnb,
                                               h16* __restrict__ out) {
    int wave = threadIdx.x >> 6, lane = threadIdx.x & 63;
    int grp = blockIdx.x * 4 + wave;     // tok*16 + h
    int h = grp & 15;
    float val = o[(size_t)grp * 64 + lane];
    float s = val, s2 = val * val;
    #pragma unroll
    for (int m = 1; m < 64; m <<= 1) {
        s  += __shfl_xor(s, m, 64);
        s2 += __shfl_xor(s2, m, 64);
    }
    float mean = s * (1.f / 64.f);
    float var  = s2 * (1.f / 64.f) - mean * mean;
    float y = (val - mean) * rsqrtf(var + 0.00064f);
    int d = h * 64 + lane;
    y = y * gnw[d] + gnb[d];
    y *= g[(size_t)grp * 64 + lane];
    out[(size_t)grp * 64 + lane] = (h16)y;
}

// ---------------------------------------------------------------------------
extern "C" void kernel_launch(void* const* d_in, const int* in_sizes, int n_in,
                              void* d_out, int out_size, void* d_ws, size_t ws_size,
                              hipStream_t stream) {
    const float* x      = (const float*)d_in[0];
    const float* ddw    = (const float*)d_in[1];
    const float* mix_r  = (const float*)d_in[2];
    const float* mix_k  = (const float*)d_in[3];
    const float* mix_v  = (const float*)d_in[4];
    const float* mix_g  = (const float*)d_in[5];
    const float* mix_w  = (const float*)d_in[6];
    const float* r_w    = (const float*)d_in[7];
    const float* k_w    = (const float*)d_in[8];
    const float* v_w    = (const float*)d_in[9];
    const float* g_w    = (const float*)d_in[10];
    const float* w_w    = (const float*)d_in[11];
    const float* out_w  = (const float*)d_in[12];
    const float* gnw    = (const float*)d_in[13];
    const float* gnb    = (const float*)d_in[14];

    char* wsb = (char*)d_ws;
    const size_t MB = 1 << 20;
    h16*   wb    = (h16*)  (wsb);             // 14 MB (7 x 2MB f16 weights)
    h16*   xs    = (h16*)  (wsb + 14 * MB);   //  8 MB
    float* dd    = (float*)(wsb + 22 * MB);   // 16 MB
    h16*   a_r   = (h16*)  (wsb + 38 * MB);   //  8 MB each
    h16*   a_k   = (h16*)  (wsb + 46 * MB);
    h16*   a_v   = (h16*)  (wsb + 54 * MB);
    h16*   a_g   = (h16*)  (wsb + 62 * MB);
    h16*   a_w   = (h16*)  (wsb + 70 * MB);
    float* rb    = (float*)(wsb + 78 * MB);   // 16 MB each
    float* kb    = (float*)(wsb + 94 * MB);
    float* vb    = (float*)(wsb + 110 * MB);
    float* gb    = (float*)(wsb + 126 * MB);
    float* ewb   = (float*)(wsb + 142 * MB);
    float* obuf  = (float*)(wsb + 158 * MB);  // 16 MB
    h16*   gated = (h16*)  (wsb + 174 * MB);  //  8 MB  (end: 182 MB)
    // overlays on the a_* region (dead once the 5 projections are done):
    float* Abuf  = (float*)(wsb + 38 * MB);   // 16.78 MB
    float* Sbuf  = (float*)(wsb + 55 * MB);   // 16.78 MB
    float* Pbuf  = (float*)(wsb + 72 * MB);   //  0.25 MB

    // 1. weights -> f16
    cvt_w7<<<7 * 512, 256, 0, stream>>>(ddw, r_w, k_w, v_w, g_w, w_w, out_w, wb);
    // 2. x_shift -> f16
    mk_xs<<<2048, 256, 0, stream>>>(x, xs);
    // 3. dd = sigmoid(tanh(xs @ ddw^T))
    dim3 gg(8, 32);
    gemm_bt<<<gg, 256, 0, stream>>>(xs, wb, dd, 1);
    // 4. 5-way lerp -> f16 activations
    lerp5<<<4096, 256, 0, stream>>>(x, dd, mix_r, mix_k, mix_v, mix_g, mix_w,
                                    a_r, a_k, a_v, a_g, a_w);
    // 5. batched projections (r,k,v,g-silu,w-exp)
    dim3 gg5(8, 32, 5);
    gemm5<<<gg5, 256, 0, stream>>>(a_r, a_k, a_v, a_g, a_w, wb, rb, kb, vb, gb, ewb);
    // 6-8. chunked WKV scan
    wkv_pass1<<<32 * NC, 256, 0, stream>>>(kb, vb, ewb, Abuf, Pbuf);
    wkv_combine<<<32, 256, 0, stream>>>(Abuf, Pbuf, Sbuf);
    wkv_pass2<<<32 * NC, 256, 0, stream>>>(rb, kb, vb, ewb, Sbuf, obuf);
    // 9. GroupNorm + gate
    gn_gate<<<(int)((size_t)Bsz * Tsz * Hn / 4), 256, 0, stream>>>(obuf, gb, gnw, gnb, gated);
    // 10. output projection
    gemm_bt<<<gg, 256, 0, stream>>>(gated, wb + 6 * 1048576, (float*)d_out, 0);
    (void)in_sizes; (void)n_in; (void)out_size; (void)ws_size;
}